// Round 1
// baseline (1490.608 us; speedup 1.0000x reference)
//
#include <hip/hip_runtime.h>
#include <math.h>

// Problem constants (from reference)
#define U_N 2048
#define I_N 16384
#define F_N 64
#define H_N 32
#define KDIM 16384     // item dimension of A
#define NEGV (-1e30f)

// ---------------- degrees ----------------
__global__ __launch_bounds__(256) void k_deg(const int* __restrict__ src,
                                             const int* __restrict__ dst, int E,
                                             int* __restrict__ deg_u,
                                             int* __restrict__ deg_i) {
    int e = blockIdx.x * 256 + threadIdx.x;
    if (e >= E) return;
    atomicAdd(&deg_u[src[e]], 1);
    atomicAdd(&deg_i[dst[e]], 1);
}

// ---------------- log1p degrees, Dh, d_u output ----------------
__global__ __launch_bounds__(256) void k_node(const int* __restrict__ deg_u,
                                              const int* __restrict__ deg_i,
                                              float* __restrict__ du,
                                              float* __restrict__ di,
                                              float* __restrict__ Dh,
                                              float* __restrict__ out_du) {
    int t = blockIdx.x * 256 + threadIdx.x;
    if (t < U_N) {
        float v = log1pf((float)deg_u[t]);
        du[t] = v;
        Dh[t] = sqrtf(v);
        out_du[t] = v;   // second output of the reference
    }
    if (t < I_N) di[t] = log1pf((float)deg_i[t]);
}

// ---------------- per-user projection P_u[u][j] ----------------
// P_u = b1[j] + sum_f x[u][f]*w1[j][f] + du[u]*w1[j][64]
__global__ __launch_bounds__(256) void k_proj_u(const float* __restrict__ x,
                                                const float* __restrict__ w1,
                                                const float* __restrict__ b1,
                                                const float* __restrict__ du,
                                                float* __restrict__ Pu) {
    int t = blockIdx.x * 256 + threadIdx.x;
    if (t >= U_N * H_N) return;
    int u = t >> 5, j = t & 31;
    const float* xr = x + (size_t)u * F_N;
    const float* wr = w1 + (size_t)j * (2 * F_N + 2);
    float acc = b1[j] + du[u] * wr[64];
#pragma unroll
    for (int f = 0; f < F_N; ++f) acc = fmaf(xr[f], wr[f], acc);
    Pu[t] = acc;
}

// ---------------- per-item projection P_i[i][j] ----------------
// P_i = sum_f x[U+i][f]*w1[j][65+f] + di[i]*w1[j][129]
__global__ __launch_bounds__(256) void k_proj_i(const float* __restrict__ x,
                                                const float* __restrict__ w1,
                                                const float* __restrict__ di,
                                                float* __restrict__ Pi) {
    int t = blockIdx.x * 256 + threadIdx.x;
    if (t >= I_N * H_N) return;
    int i = t >> 5, j = t & 31;
    const float* xr = x + (size_t)(U_N + i) * F_N;
    const float* wr = w1 + (size_t)j * (2 * F_N + 2) + 65;
    float acc = di[i] * wr[64];  // w1[j][129]
#pragma unroll
    for (int f = 0; f < F_N; ++f) acc = fmaf(xr[f], wr[f], acc);
    Pi[t] = acc;
}

// ---------------- per-edge weight + scatter into dense A ----------------
__global__ __launch_bounds__(256) void k_edge(const int* __restrict__ src,
                                              const int* __restrict__ dst, int E,
                                              const float* __restrict__ Pu,
                                              const float* __restrict__ Pi,
                                              const float* __restrict__ w2,
                                              const float* __restrict__ b2,
                                              float* __restrict__ A) {
    int e = blockIdx.x * 256 + threadIdx.x;
    if (e >= E) return;
    int u = src[e], i = dst[e];
    const float4* pu = (const float4*)(Pu + (size_t)u * H_N);
    const float4* pi = (const float4*)(Pi + (size_t)i * H_N);
    const float4* wv = (const float4*)w2;
    float acc = b2[0];
#pragma unroll
    for (int q = 0; q < H_N / 4; ++q) {
        float4 a = pu[q], b = pi[q], w = wv[q];
        acc = fmaf(fmaxf(a.x + b.x, 0.f), w.x, acc);
        acc = fmaf(fmaxf(a.y + b.y, 0.f), w.y, acc);
        acc = fmaf(fmaxf(a.z + b.z, 0.f), w.z, acc);
        acc = fmaf(fmaxf(a.w + b.w, 0.f), w.w, acc);
    }
    float wgt = 1.0f / (1.0f + expf(-acc));
    atomicAdd(&A[(size_t)u * I_N + i], wgt);
}

// ---------------- C = A * A^T (symmetric, fp32) ----------------
// 128x128 tiles over block-pairs (bi<=bj), KSPLIT partial-K per block,
// accumulate with atomicAdd into C; mirror off-diagonal tiles.
#define BM 128
#define BK 16
#define NBLK (U_N / BM)      // 16
#define KSPLIT 4
#define KCH (KDIM / KSPLIT)  // 4096

__global__ __launch_bounds__(256) void k_syrk(const float* __restrict__ A,
                                              float* __restrict__ C) {
    __shared__ float As[BK][BM + 4];
    __shared__ float Bs[BK][BM + 4];

    // decode pair index -> (bi, bj), bi <= bj
    int p = blockIdx.x;
    int bi = 0, rem = p;
    while (rem >= NBLK - bi) { rem -= NBLK - bi; ++bi; }
    int bj = bi + rem;
    int k0 = blockIdx.y * KCH;

    int tid = threadIdx.x;
    int lrow = tid >> 1;          // 0..127
    int lk = (tid & 1) * 8;       // 0 or 8

    const float* Ab = A + (size_t)(bi * BM + lrow) * KDIM + k0 + lk;
    const float* Bb = A + (size_t)(bj * BM + lrow) * KDIM + k0 + lk;

    int ty = tid >> 4, tx = tid & 15;
    int r0 = ty * 4, r1 = ty * 4 + 64;
    int c0 = tx * 4, c1 = tx * 4 + 64;

    float acc[8][8];
#pragma unroll
    for (int m = 0; m < 8; ++m)
#pragma unroll
        for (int n = 0; n < 8; ++n) acc[m][n] = 0.f;

    for (int kt = 0; kt < KCH; kt += BK) {
        float4 a0 = *(const float4*)(Ab + kt);
        float4 a1 = *(const float4*)(Ab + kt + 4);
        float4 b0 = *(const float4*)(Bb + kt);
        float4 b1 = *(const float4*)(Bb + kt + 4);
        __syncthreads();
        As[lk + 0][lrow] = a0.x; As[lk + 1][lrow] = a0.y;
        As[lk + 2][lrow] = a0.z; As[lk + 3][lrow] = a0.w;
        As[lk + 4][lrow] = a1.x; As[lk + 5][lrow] = a1.y;
        As[lk + 6][lrow] = a1.z; As[lk + 7][lrow] = a1.w;
        Bs[lk + 0][lrow] = b0.x; Bs[lk + 1][lrow] = b0.y;
        Bs[lk + 2][lrow] = b0.z; Bs[lk + 3][lrow] = b0.w;
        Bs[lk + 4][lrow] = b1.x; Bs[lk + 5][lrow] = b1.y;
        Bs[lk + 6][lrow] = b1.z; Bs[lk + 7][lrow] = b1.w;
        __syncthreads();
#pragma unroll
        for (int k = 0; k < BK; ++k) {
            const float4 av0 = *(const float4*)(&As[k][r0]);
            const float4 av1 = *(const float4*)(&As[k][r1]);
            const float4 bv0 = *(const float4*)(&Bs[k][c0]);
            const float4 bv1 = *(const float4*)(&Bs[k][c1]);
            float am[8] = {av0.x, av0.y, av0.z, av0.w, av1.x, av1.y, av1.z, av1.w};
            float bn[8] = {bv0.x, bv0.y, bv0.z, bv0.w, bv1.x, bv1.y, bv1.z, bv1.w};
#pragma unroll
            for (int m = 0; m < 8; ++m)
#pragma unroll
                for (int n = 0; n < 8; ++n)
                    acc[m][n] = fmaf(am[m], bn[n], acc[m][n]);
        }
    }

    int grow = bi * BM, gcol = bj * BM;
#pragma unroll
    for (int m = 0; m < 8; ++m) {
        int r = grow + ((m < 4) ? (r0 + m) : (r1 + m - 4));
#pragma unroll
        for (int n = 0; n < 8; ++n) {
            int c = gcol + ((n < 4) ? (c0 + n) : (c1 + n - 4));
            atomicAdd(&C[(size_t)r * U_N + c], acc[m][n]);
            if (bi != bj) atomicAdd(&C[(size_t)c * U_N + r], acc[m][n]);
        }
    }
}

// ---------------- top-3 per row (scaled by Dh outer product) ----------------
__device__ __forceinline__ bool better(float va, int ia, float vb, int ib) {
    return (va > vb) || (va == vb && ia < ib);
}
__device__ __forceinline__ void ins3(float v, int i, float& v0, int& i0,
                                     float& v1, int& i1, float& v2, int& i2) {
    if (better(v, i, v0, i0)) { v2 = v1; i2 = i1; v1 = v0; i1 = i0; v0 = v; i0 = i; }
    else if (better(v, i, v1, i1)) { v2 = v1; i2 = i1; v1 = v; i1 = i; }
    else if (better(v, i, v2, i2)) { v2 = v; i2 = i; }
}

__global__ __launch_bounds__(64) void k_topk(const float* __restrict__ C,
                                             const float* __restrict__ Dh,
                                             float* __restrict__ topv,
                                             int* __restrict__ topi) {
    int r = blockIdx.x;
    int lane = threadIdx.x;
    float dr = Dh[r];
    const float* row = C + (size_t)r * U_N;
    float v0 = NEGV, v1 = NEGV, v2 = NEGV;
    int i0 = 0x7fffffff, i1 = 0x7fffffff, i2 = 0x7fffffff;
    for (int c = lane; c < U_N; c += 64) {
        float cv = row[c];
        float val = (cv > 0.f) ? cv * dr * Dh[c] : NEGV;
        if (better(val, c, v2, i2)) ins3(val, c, v0, i0, v1, i1, v2, i2);
    }
    // butterfly merge across 64 lanes (disjoint halves each stage)
#pragma unroll
    for (int off = 1; off < 64; off <<= 1) {
        float ov0 = __shfl_xor(v0, off), ov1 = __shfl_xor(v1, off), ov2 = __shfl_xor(v2, off);
        int oi0 = __shfl_xor(i0, off), oi1 = __shfl_xor(i1, off), oi2 = __shfl_xor(i2, off);
        ins3(ov0, oi0, v0, i0, v1, i1, v2, i2);
        ins3(ov1, oi1, v0, i0, v1, i1, v2, i2);
        ins3(ov2, oi2, v0, i0, v1, i1, v2, i2);
    }
    if (lane == 0) {
        topv[r * 3 + 0] = v0; topi[r * 3 + 0] = i0;
        topv[r * 3 + 1] = v1; topi[r * 3 + 1] = i1;
        topv[r * 3 + 2] = v2; topi[r * 3 + 2] = i2;
    }
}

// ---------------- scatter S = T + T^T ----------------
__global__ __launch_bounds__(256) void k_scatter(const float* __restrict__ topv,
                                                 const int* __restrict__ topi,
                                                 float* __restrict__ out) {
    int r = blockIdx.x * 256 + threadIdx.x;
    if (r >= U_N) return;
#pragma unroll
    for (int k = 0; k < 3; ++k) {
        float v = topv[r * 3 + k];
        int c = topi[r * 3 + k];
        if (v > 0.f) {
            atomicAdd(&out[(size_t)r * U_N + c], 0.5f * v);
            atomicAdd(&out[(size_t)c * U_N + r], 0.5f * v);
        }
    }
}

extern "C" void kernel_launch(void* const* d_in, const int* in_sizes, int n_in,
                              void* d_out, int out_size, void* d_ws, size_t ws_size,
                              hipStream_t stream) {
    const float* x  = (const float*)d_in[0];
    const float* w1 = (const float*)d_in[1];
    const float* b1 = (const float*)d_in[2];
    const float* w2 = (const float*)d_in[3];
    const float* b2 = (const float*)d_in[4];
    const int* esrc = (const int*)d_in[5];
    const int* edst = (const int*)d_in[6];
    int E = in_sizes[5];
    float* out = (float*)d_out;

    // workspace layout (~153.6 MB)
    float* A    = (float*)d_ws;                       // U*I
    float* C    = A + (size_t)U_N * I_N;              // U*U
    float* Pu   = C + (size_t)U_N * U_N;              // U*H
    float* Pi   = Pu + (size_t)U_N * H_N;             // I*H
    int*   degu = (int*)(Pi + (size_t)I_N * H_N);     // U
    int*   degi = degu + U_N;                         // I
    float* du   = (float*)(degi + I_N);               // U
    float* di   = du + U_N;                           // I
    float* Dh   = di + I_N;                           // U
    float* topv = Dh + U_N;                           // U*3
    int*   topi = (int*)(topv + U_N * 3);             // U*3

    hipMemsetAsync(A, 0, (size_t)U_N * I_N * sizeof(float), stream);
    hipMemsetAsync(C, 0, (size_t)U_N * U_N * sizeof(float), stream);
    hipMemsetAsync(degu, 0, (size_t)(U_N + I_N) * sizeof(int), stream);
    hipMemsetAsync(out, 0, (size_t)out_size * sizeof(float), stream);

    k_deg<<<(E + 255) / 256, 256, 0, stream>>>(esrc, edst, E, degu, degi);
    k_node<<<(I_N + 255) / 256, 256, 0, stream>>>(degu, degi, du, di, Dh,
                                                  out + (size_t)U_N * U_N);
    k_proj_u<<<(U_N * H_N) / 256, 256, 0, stream>>>(x, w1, b1, du, Pu);
    k_proj_i<<<(I_N * H_N) / 256, 256, 0, stream>>>(x, w1, di, Pi);
    k_edge<<<(E + 255) / 256, 256, 0, stream>>>(esrc, edst, E, Pu, Pi, w2, b2, A);
    k_syrk<<<dim3(NBLK * (NBLK + 1) / 2, KSPLIT), 256, 0, stream>>>(A, C);
    k_topk<<<U_N, 64, 0, stream>>>(C, Dh, topv, topi);
    k_scatter<<<(U_N + 255) / 256, 256, 0, stream>>>(topv, topi, out);
}

// Round 2
// 738.249 us; speedup vs baseline: 2.0191x; 2.0191x over previous
//
#include <hip/hip_runtime.h>
#include <hip/hip_bf16.h>
#include <math.h>

// Problem constants (from reference)
#define U_N 2048
#define I_N 16384
#define F_N 64
#define H_N 32
#define KDIM 16384     // item dimension of A
#define NEGV (-1e30f)

typedef __attribute__((ext_vector_type(8))) short short8;   // 8 bf16 (4 VGPR)
typedef __attribute__((ext_vector_type(4))) float f32x4;    // MFMA accumulator

// ---------------- degrees ----------------
__global__ __launch_bounds__(256) void k_deg(const int* __restrict__ src,
                                             const int* __restrict__ dst, int E,
                                             int* __restrict__ deg_u,
                                             int* __restrict__ deg_i) {
    int e = blockIdx.x * 256 + threadIdx.x;
    if (e >= E) return;
    atomicAdd(&deg_u[src[e]], 1);
    atomicAdd(&deg_i[dst[e]], 1);
}

// ---------------- log1p degrees, Dh, d_u output ----------------
__global__ __launch_bounds__(256) void k_node(const int* __restrict__ deg_u,
                                              const int* __restrict__ deg_i,
                                              float* __restrict__ du,
                                              float* __restrict__ di,
                                              float* __restrict__ Dh,
                                              float* __restrict__ out_du) {
    int t = blockIdx.x * 256 + threadIdx.x;
    if (t < U_N) {
        float v = log1pf((float)deg_u[t]);
        du[t] = v;
        Dh[t] = sqrtf(v);
        out_du[t] = v;   // second output of the reference
    }
    if (t < I_N) di[t] = log1pf((float)deg_i[t]);
}

// ---------------- per-user projection P_u[u][j] ----------------
__global__ __launch_bounds__(256) void k_proj_u(const float* __restrict__ x,
                                                const float* __restrict__ w1,
                                                const float* __restrict__ b1,
                                                const float* __restrict__ du,
                                                float* __restrict__ Pu) {
    int t = blockIdx.x * 256 + threadIdx.x;
    if (t >= U_N * H_N) return;
    int u = t >> 5, j = t & 31;
    const float* xr = x + (size_t)u * F_N;
    const float* wr = w1 + (size_t)j * (2 * F_N + 2);
    float acc = b1[j] + du[u] * wr[64];
#pragma unroll
    for (int f = 0; f < F_N; ++f) acc = fmaf(xr[f], wr[f], acc);
    Pu[t] = acc;
}

// ---------------- per-item projection P_i[i][j] ----------------
__global__ __launch_bounds__(256) void k_proj_i(const float* __restrict__ x,
                                                const float* __restrict__ w1,
                                                const float* __restrict__ di,
                                                float* __restrict__ Pi) {
    int t = blockIdx.x * 256 + threadIdx.x;
    if (t >= I_N * H_N) return;
    int i = t >> 5, j = t & 31;
    const float* xr = x + (size_t)(U_N + i) * F_N;
    const float* wr = w1 + (size_t)j * (2 * F_N + 2) + 65;
    float acc = di[i] * wr[64];  // w1[j][129]
#pragma unroll
    for (int f = 0; f < F_N; ++f) acc = fmaf(xr[f], wr[f], acc);
    Pi[t] = acc;
}

// ---------------- per-edge weight + scatter into dense A ----------------
__global__ __launch_bounds__(256) void k_edge(const int* __restrict__ src,
                                              const int* __restrict__ dst, int E,
                                              const float* __restrict__ Pu,
                                              const float* __restrict__ Pi,
                                              const float* __restrict__ w2,
                                              const float* __restrict__ b2,
                                              float* __restrict__ A) {
    int e = blockIdx.x * 256 + threadIdx.x;
    if (e >= E) return;
    int u = src[e], i = dst[e];
    const float4* pu = (const float4*)(Pu + (size_t)u * H_N);
    const float4* pi = (const float4*)(Pi + (size_t)i * H_N);
    const float4* wv = (const float4*)w2;
    float acc = b2[0];
#pragma unroll
    for (int q = 0; q < H_N / 4; ++q) {
        float4 a = pu[q], b = pi[q], w = wv[q];
        acc = fmaf(fmaxf(a.x + b.x, 0.f), w.x, acc);
        acc = fmaf(fmaxf(a.y + b.y, 0.f), w.y, acc);
        acc = fmaf(fmaxf(a.z + b.z, 0.f), w.z, acc);
        acc = fmaf(fmaxf(a.w + b.w, 0.f), w.w, acc);
    }
    float wgt = 1.0f / (1.0f + expf(-acc));
    atomicAdd(&A[(size_t)u * I_N + i], wgt);
}

// ---------------- C = A * A^T via bf16 MFMA ----------------
// 128x128 tiles over symmetric block-pairs (bi<=bj), KSPLIT partial-K,
// fp32 A staged through registers -> bf16 pack -> LDS, 16x16x32 MFMA,
// fp32 atomicAdd epilogue (mirror for off-diagonal pairs).
#define BM 128
#define BK 32
#define NBLK (U_N / BM)                 // 16
#define NPAIR (NBLK * (NBLK + 1) / 2)   // 136
#define KSPLIT 4
#define KCH (KDIM / KSPLIT)             // 4096

// round-half-up f32->bf16, packed pair (lo in low 16 bits)
__device__ __forceinline__ unsigned int pk2(float lo, float hi) {
    unsigned int a = __builtin_bit_cast(unsigned int, lo);
    unsigned int b = __builtin_bit_cast(unsigned int, hi);
    return ((a + 0x8000u) >> 16) | ((b + 0x8000u) & 0xffff0000u);
}
__device__ __forceinline__ uint4 pack8(float4 a, float4 b) {
    uint4 r;
    r.x = pk2(a.x, a.y); r.y = pk2(a.z, a.w);
    r.z = pk2(b.x, b.y); r.w = pk2(b.z, b.w);
    return r;
}

__global__ __launch_bounds__(256) void k_syrk_mfma(const float* __restrict__ A,
                                                   float* __restrict__ C) {
    __shared__ unsigned short As[BM][BK];   // 8 KB, bf16 bits, 64B rows
    __shared__ unsigned short Bs[BM][BK];   // 8 KB

    // decode pair index -> (bi, bj), bi <= bj
    int p = blockIdx.x;
    int bi = 0, rem = p;
    while (rem >= NBLK - bi) { rem -= NBLK - bi; ++bi; }
    int bj = bi + rem;
    int k0 = blockIdx.y * KCH;

    int tid = threadIdx.x;
    // staging: lane-contiguous LDS writes. thread t -> (row = t>>2 [+64], q8 = t&3)
    // writes 16B (8 bf16) at As[row][q8*8], sourced from 2 float4 global loads.
    int srow = tid >> 2;
    int sq = tid & 3;
    const float* Ag = A + (size_t)(bi * BM + srow) * KDIM + k0 + sq * 8;
    const float* Bg = A + (size_t)(bj * BM + srow) * KDIM + k0 + sq * 8;
    const float* Ag2 = Ag + (size_t)64 * KDIM;
    const float* Bg2 = Bg + (size_t)64 * KDIM;
    uint4* AsW = (uint4*)(&As[srow][sq * 8]);
    uint4* AsW2 = (uint4*)(&As[srow + 64][sq * 8]);
    uint4* BsW = (uint4*)(&Bs[srow][sq * 8]);
    uint4* BsW2 = (uint4*)(&Bs[srow + 64][sq * 8]);

    // MFMA coords: 4 waves, each a 64x64 quadrant (4x4 of 16x16 tiles)
    int wave = tid >> 6;
    int lane = tid & 63;
    int wm = wave >> 1, wn = wave & 1;
    int lm = lane & 15;     // A/B fragment row (m / n), also C col
    int lq = lane >> 4;     // k-quad for frags; row-quad for C/D

    const unsigned short* aBase = &As[wm * 64 + lm][lq * 8];
    const unsigned short* bBase = &Bs[wn * 64 + lm][lq * 8];

    f32x4 acc[4][4];
#pragma unroll
    for (int m = 0; m < 4; ++m)
#pragma unroll
        for (int n = 0; n < 4; ++n) acc[m][n] = (f32x4){0.f, 0.f, 0.f, 0.f};

    for (int kt = 0; kt < KCH; kt += BK) {
        float4 a0 = *(const float4*)(Ag + kt);
        float4 a1 = *(const float4*)(Ag + kt + 4);
        float4 a2 = *(const float4*)(Ag2 + kt);
        float4 a3 = *(const float4*)(Ag2 + kt + 4);
        float4 b0 = *(const float4*)(Bg + kt);
        float4 b1 = *(const float4*)(Bg + kt + 4);
        float4 b2 = *(const float4*)(Bg2 + kt);
        float4 b3 = *(const float4*)(Bg2 + kt + 4);
        __syncthreads();
        *AsW = pack8(a0, a1);
        *AsW2 = pack8(a2, a3);
        *BsW = pack8(b0, b1);
        *BsW2 = pack8(b2, b3);
        __syncthreads();

        short8 av[4], bv[4];
#pragma unroll
        for (int m = 0; m < 4; ++m) av[m] = *(const short8*)(aBase + m * 16 * BK);
#pragma unroll
        for (int n = 0; n < 4; ++n) bv[n] = *(const short8*)(bBase + n * 16 * BK);
#pragma unroll
        for (int m = 0; m < 4; ++m)
#pragma unroll
            for (int n = 0; n < 4; ++n)
                acc[m][n] = __builtin_amdgcn_mfma_f32_16x16x32_bf16(
                    av[m], bv[n], acc[m][n], 0, 0, 0);
    }

    // epilogue: C/D layout col=lane&15, row=lq*4+reg  (m89-verified)
    int mirror = (bi != bj);
#pragma unroll
    for (int m = 0; m < 4; ++m) {
        int rb = bi * BM + wm * 64 + m * 16 + lq * 4;
#pragma unroll
        for (int n = 0; n < 4; ++n) {
            int c = bj * BM + wn * 64 + n * 16 + lm;
            f32x4 v = acc[m][n];
#pragma unroll
            for (int g = 0; g < 4; ++g) {
                int r = rb + g;
                atomicAdd(&C[(size_t)r * U_N + c], v[g]);
                if (mirror) atomicAdd(&C[(size_t)c * U_N + r], v[g]);
            }
        }
    }
}

// ---------------- top-3 per row (scaled by Dh outer product) ----------------
__device__ __forceinline__ bool better(float va, int ia, float vb, int ib) {
    return (va > vb) || (va == vb && ia < ib);
}
__device__ __forceinline__ void ins3(float v, int i, float& v0, int& i0,
                                     float& v1, int& i1, float& v2, int& i2) {
    if (better(v, i, v0, i0)) { v2 = v1; i2 = i1; v1 = v0; i1 = i0; v0 = v; i0 = i; }
    else if (better(v, i, v1, i1)) { v2 = v1; i2 = i1; v1 = v; i1 = i; }
    else if (better(v, i, v2, i2)) { v2 = v; i2 = i; }
}

__global__ __launch_bounds__(64) void k_topk(const float* __restrict__ C,
                                             const float* __restrict__ Dh,
                                             float* __restrict__ topv,
                                             int* __restrict__ topi) {
    int r = blockIdx.x;
    int lane = threadIdx.x;
    float dr = Dh[r];
    const float* row = C + (size_t)r * U_N;
    float v0 = NEGV, v1 = NEGV, v2 = NEGV;
    int i0 = 0x7fffffff, i1 = 0x7fffffff, i2 = 0x7fffffff;
    for (int c = lane; c < U_N; c += 64) {
        float cv = row[c];
        float val = (cv > 0.f) ? cv * dr * Dh[c] : NEGV;
        if (better(val, c, v2, i2)) ins3(val, c, v0, i0, v1, i1, v2, i2);
    }
#pragma unroll
    for (int off = 1; off < 64; off <<= 1) {
        float ov0 = __shfl_xor(v0, off), ov1 = __shfl_xor(v1, off), ov2 = __shfl_xor(v2, off);
        int oi0 = __shfl_xor(i0, off), oi1 = __shfl_xor(i1, off), oi2 = __shfl_xor(i2, off);
        ins3(ov0, oi0, v0, i0, v1, i1, v2, i2);
        ins3(ov1, oi1, v0, i0, v1, i1, v2, i2);
        ins3(ov2, oi2, v0, i0, v1, i1, v2, i2);
    }
    if (lane == 0) {
        topv[r * 3 + 0] = v0; topi[r * 3 + 0] = i0;
        topv[r * 3 + 1] = v1; topi[r * 3 + 1] = i1;
        topv[r * 3 + 2] = v2; topi[r * 3 + 2] = i2;
    }
}

// ---------------- scatter S = T + T^T ----------------
__global__ __launch_bounds__(256) void k_scatter(const float* __restrict__ topv,
                                                 const int* __restrict__ topi,
                                                 float* __restrict__ out) {
    int r = blockIdx.x * 256 + threadIdx.x;
    if (r >= U_N) return;
#pragma unroll
    for (int k = 0; k < 3; ++k) {
        float v = topv[r * 3 + k];
        int c = topi[r * 3 + k];
        if (v > 0.f) {
            atomicAdd(&out[(size_t)r * U_N + c], 0.5f * v);
            atomicAdd(&out[(size_t)c * U_N + r], 0.5f * v);
        }
    }
}

extern "C" void kernel_launch(void* const* d_in, const int* in_sizes, int n_in,
                              void* d_out, int out_size, void* d_ws, size_t ws_size,
                              hipStream_t stream) {
    const float* x  = (const float*)d_in[0];
    const float* w1 = (const float*)d_in[1];
    const float* b1 = (const float*)d_in[2];
    const float* w2 = (const float*)d_in[3];
    const float* b2 = (const float*)d_in[4];
    const int* esrc = (const int*)d_in[5];
    const int* edst = (const int*)d_in[6];
    int E = in_sizes[5];
    float* out = (float*)d_out;

    // workspace layout (~153.6 MB)
    float* A    = (float*)d_ws;                       // U*I
    float* C    = A + (size_t)U_N * I_N;              // U*U
    float* Pu   = C + (size_t)U_N * U_N;              // U*H
    float* Pi   = Pu + (size_t)U_N * H_N;             // I*H
    int*   degu = (int*)(Pi + (size_t)I_N * H_N);     // U
    int*   degi = degu + U_N;                         // I
    float* du   = (float*)(degi + I_N);               // U
    float* di   = du + U_N;                           // I
    float* Dh   = di + I_N;                           // U
    float* topv = Dh + U_N;                           // U*3
    int*   topi = (int*)(topv + U_N * 3);             // U*3

    hipMemsetAsync(A, 0, (size_t)U_N * I_N * sizeof(float), stream);
    hipMemsetAsync(C, 0, (size_t)U_N * U_N * sizeof(float), stream);
    hipMemsetAsync(degu, 0, (size_t)(U_N + I_N) * sizeof(int), stream);
    hipMemsetAsync(out, 0, (size_t)out_size * sizeof(float), stream);

    k_deg<<<(E + 255) / 256, 256, 0, stream>>>(esrc, edst, E, degu, degi);
    k_node<<<(I_N + 255) / 256, 256, 0, stream>>>(degu, degi, du, di, Dh,
                                                  out + (size_t)U_N * U_N);
    k_proj_u<<<(U_N * H_N) / 256, 256, 0, stream>>>(x, w1, b1, du, Pu);
    k_proj_i<<<(I_N * H_N) / 256, 256, 0, stream>>>(x, w1, di, Pi);
    k_edge<<<(E + 255) / 256, 256, 0, stream>>>(esrc, edst, E, Pu, Pi, w2, b2, A);
    k_syrk_mfma<<<dim3(NPAIR, KSPLIT), 256, 0, stream>>>(A, C);
    k_topk<<<U_N, 64, 0, stream>>>(C, Dh, topv, topi);
    k_scatter<<<(U_N + 255) / 256, 256, 0, stream>>>(topv, topi, out);
}

// Round 3
// 653.757 us; speedup vs baseline: 2.2801x; 1.1292x over previous
//
#include <hip/hip_runtime.h>
#include <hip/hip_bf16.h>
#include <math.h>

// Problem constants (from reference)
#define U_N 2048
#define I_N 16384
#define F_N 64
#define H_N 32
#define KDIM 16384     // item dimension of A
#define NEGV (-1e30f)

typedef __attribute__((ext_vector_type(8))) short short8;   // 8 bf16 (4 VGPR)
typedef __attribute__((ext_vector_type(4))) float f32x4;    // MFMA accumulator

// f32 -> bf16 bits, round-to-nearest-even
__device__ __forceinline__ unsigned short f2bf(float f) {
    unsigned int u = __builtin_bit_cast(unsigned int, f);
    return (unsigned short)((u + 0x7fffu + ((u >> 16) & 1u)) >> 16);
}
__device__ __forceinline__ float bf2f(unsigned short h) {
    unsigned int u = ((unsigned int)h) << 16;
    return __builtin_bit_cast(float, u);
}

// async global -> LDS, 16B per lane (wave-uniform LDS base + lane*16)
__device__ __forceinline__ void gload16(const unsigned short* g, unsigned short* l) {
    __builtin_amdgcn_global_load_lds(
        (const __attribute__((address_space(1))) unsigned int*)g,
        (__attribute__((address_space(3))) unsigned int*)l, 16, 0, 0);
}

// ---------------- degrees ----------------
__global__ __launch_bounds__(256) void k_deg(const int* __restrict__ src,
                                             const int* __restrict__ dst, int E,
                                             int* __restrict__ deg_u,
                                             int* __restrict__ deg_i) {
    int e = blockIdx.x * 256 + threadIdx.x;
    if (e >= E) return;
    atomicAdd(&deg_u[src[e]], 1);
    atomicAdd(&deg_i[dst[e]], 1);
}

// ---------------- log1p degrees, Dh, d_u output ----------------
__global__ __launch_bounds__(256) void k_node(const int* __restrict__ deg_u,
                                              const int* __restrict__ deg_i,
                                              float* __restrict__ du,
                                              float* __restrict__ di,
                                              float* __restrict__ Dh,
                                              float* __restrict__ out_du) {
    int t = blockIdx.x * 256 + threadIdx.x;
    if (t < U_N) {
        float v = log1pf((float)deg_u[t]);
        du[t] = v;
        Dh[t] = sqrtf(v);
        out_du[t] = v;   // second output of the reference
    }
    if (t < I_N) di[t] = log1pf((float)deg_i[t]);
}

// ---------------- per-user projection P_u[u][j] ----------------
__global__ __launch_bounds__(256) void k_proj_u(const float* __restrict__ x,
                                                const float* __restrict__ w1,
                                                const float* __restrict__ b1,
                                                const float* __restrict__ du,
                                                float* __restrict__ Pu) {
    int t = blockIdx.x * 256 + threadIdx.x;
    if (t >= U_N * H_N) return;
    int u = t >> 5, j = t & 31;
    const float* xr = x + (size_t)u * F_N;
    const float* wr = w1 + (size_t)j * (2 * F_N + 2);
    float acc = b1[j] + du[u] * wr[64];
#pragma unroll
    for (int f = 0; f < F_N; ++f) acc = fmaf(xr[f], wr[f], acc);
    Pu[t] = acc;
}

// ---------------- per-item projection P_i[i][j] ----------------
__global__ __launch_bounds__(256) void k_proj_i(const float* __restrict__ x,
                                                const float* __restrict__ w1,
                                                const float* __restrict__ di,
                                                float* __restrict__ Pi) {
    int t = blockIdx.x * 256 + threadIdx.x;
    if (t >= I_N * H_N) return;
    int i = t >> 5, j = t & 31;
    const float* xr = x + (size_t)(U_N + i) * F_N;
    const float* wr = w1 + (size_t)j * (2 * F_N + 2) + 65;
    float acc = di[i] * wr[64];  // w1[j][129]
#pragma unroll
    for (int f = 0; f < F_N; ++f) acc = fmaf(xr[f], wr[f], acc);
    Pi[t] = acc;
}

// ---------------- per-edge weight + bf16 CAS-accumulate into A ----------------
__global__ __launch_bounds__(256) void k_edge(const int* __restrict__ src,
                                              const int* __restrict__ dst, int E,
                                              const float* __restrict__ Pu,
                                              const float* __restrict__ Pi,
                                              const float* __restrict__ w2,
                                              const float* __restrict__ b2,
                                              unsigned short* __restrict__ Abf) {
    int e = blockIdx.x * 256 + threadIdx.x;
    if (e >= E) return;
    int u = src[e], i = dst[e];
    const float4* pu = (const float4*)(Pu + (size_t)u * H_N);
    const float4* pi = (const float4*)(Pi + (size_t)i * H_N);
    const float4* wv = (const float4*)w2;
    float acc = b2[0];
#pragma unroll
    for (int q = 0; q < H_N / 4; ++q) {
        float4 a = pu[q], b = pi[q], w = wv[q];
        acc = fmaf(fmaxf(a.x + b.x, 0.f), w.x, acc);
        acc = fmaf(fmaxf(a.y + b.y, 0.f), w.y, acc);
        acc = fmaf(fmaxf(a.z + b.z, 0.f), w.z, acc);
        acc = fmaf(fmaxf(a.w + b.w, 0.f), w.w, acc);
    }
    float wgt = 1.0f / (1.0f + expf(-acc));

    // coalesce-sum duplicates in bf16 via 32-bit CAS (dups ~1.5% of edges)
    unsigned int idx = (unsigned int)u * (unsigned int)I_N + (unsigned int)i;
    unsigned int* word = (unsigned int*)Abf + (idx >> 1);
    unsigned int shift = (idx & 1u) * 16u;
    unsigned int cur = *word, assumed;
    do {
        assumed = cur;
        unsigned short h = (unsigned short)((assumed >> shift) & 0xffffu);
        unsigned short nh = f2bf(bf2f(h) + wgt);
        unsigned int nw = (assumed & ~(0xffffu << shift)) | ((unsigned int)nh << shift);
        cur = atomicCAS(word, assumed, nw);
    } while (cur != assumed);
}

// ---------------- C = A * A^T via bf16 MFMA, async LDS staging ----------------
// 128x128 tiles over symmetric block-pairs (bi<=bj), KSPLIT partial-K,
// global_load_lds (16B/lane) staging of bf16 A, 16x16x32 MFMA,
// fp32 atomicAdd epilogue (mirror for off-diagonal pairs).
#define BM 128
#define BK 32
#define NBLK (U_N / BM)                 // 16
#define NPAIR (NBLK * (NBLK + 1) / 2)   // 136
#define KSPLIT 4
#define KCH (KDIM / KSPLIT)             // 4096

__global__ __launch_bounds__(256) void k_syrk(const unsigned short* __restrict__ Abf,
                                              float* __restrict__ C) {
    __shared__ unsigned short As[BM * BK];   // 8 KB, 64B rows
    __shared__ unsigned short Bs[BM * BK];   // 8 KB

    // decode pair index -> (bi, bj), bi <= bj
    int p = blockIdx.x;
    int bi = 0, rem = p;
    while (rem >= NBLK - bi) { rem -= NBLK - bi; ++bi; }
    int bj = bi + rem;
    int k0 = blockIdx.y * KCH;
    int diag = (bi == bj);

    int tid = threadIdx.x;
    int wave = tid >> 6, lane = tid & 63;

    // staging: wave w fills segments {2w, 2w+1} of each tile.
    // segment = 16 rows x 64B; lane l -> row 16*s + l/4, 16B chunk l%4.
    int s0 = wave * 2, s1 = s0 + 1;
    int srow = lane >> 2, scol = (lane & 3) * 8;
    const unsigned short* Ag0 = Abf + (size_t)(bi * BM + s0 * 16 + srow) * KDIM + k0 + scol;
    const unsigned short* Ag1 = Abf + (size_t)(bi * BM + s1 * 16 + srow) * KDIM + k0 + scol;
    const unsigned short* Bg0 = Abf + (size_t)(bj * BM + s0 * 16 + srow) * KDIM + k0 + scol;
    const unsigned short* Bg1 = Abf + (size_t)(bj * BM + s1 * 16 + srow) * KDIM + k0 + scol;
    unsigned short* lA0 = As + s0 * 512;   // 1KB segments (wave-uniform bases)
    unsigned short* lA1 = As + s1 * 512;
    unsigned short* lB0 = Bs + s0 * 512;
    unsigned short* lB1 = Bs + s1 * 512;

    // MFMA coords: 4 waves, each a 64x64 quadrant (4x4 of 16x16 tiles)
    int wm = wave >> 1, wn = wave & 1;
    int lm = lane & 15, lq = lane >> 4;
    const unsigned short* bTile = diag ? As : Bs;
    const unsigned short* aBase = As + (wm * 64 + lm) * BK + lq * 8;
    const unsigned short* bBase = bTile + (wn * 64 + lm) * BK + lq * 8;

    f32x4 acc[4][4];
#pragma unroll
    for (int m = 0; m < 4; ++m)
#pragma unroll
        for (int n = 0; n < 4; ++n) acc[m][n] = (f32x4){0.f, 0.f, 0.f, 0.f};

    for (int kt = 0; kt < KCH; kt += BK) {
        __syncthreads();              // previous tile fully consumed
        gload16(Ag0 + kt, lA0);
        gload16(Ag1 + kt, lA1);
        if (!diag) {
            gload16(Bg0 + kt, lB0);
            gload16(Bg1 + kt, lB1);
        }
        __syncthreads();              // vmcnt(0) drain -> tile ready

        short8 av[4], bv[4];
#pragma unroll
        for (int m = 0; m < 4; ++m) av[m] = *(const short8*)(aBase + m * 16 * BK);
#pragma unroll
        for (int n = 0; n < 4; ++n) bv[n] = *(const short8*)(bBase + n * 16 * BK);
#pragma unroll
        for (int m = 0; m < 4; ++m)
#pragma unroll
            for (int n = 0; n < 4; ++n)
                acc[m][n] = __builtin_amdgcn_mfma_f32_16x16x32_bf16(
                    av[m], bv[n], acc[m][n], 0, 0, 0);
    }

    // epilogue: C/D layout col=lane&15, row=lq*4+reg  (m89-verified)
    int mirror = !diag;
#pragma unroll
    for (int m = 0; m < 4; ++m) {
        int rb = bi * BM + wm * 64 + m * 16 + lq * 4;
#pragma unroll
        for (int n = 0; n < 4; ++n) {
            int c = bj * BM + wn * 64 + n * 16 + lm;
            f32x4 v = acc[m][n];
#pragma unroll
            for (int g = 0; g < 4; ++g) {
                int r = rb + g;
                atomicAdd(&C[(size_t)r * U_N + c], v[g]);
                if (mirror) atomicAdd(&C[(size_t)c * U_N + r], v[g]);
            }
        }
    }
}

// ---------------- top-3 per row (scaled by Dh outer product) ----------------
__device__ __forceinline__ bool better(float va, int ia, float vb, int ib) {
    return (va > vb) || (va == vb && ia < ib);
}
__device__ __forceinline__ void ins3(float v, int i, float& v0, int& i0,
                                     float& v1, int& i1, float& v2, int& i2) {
    if (better(v, i, v0, i0)) { v2 = v1; i2 = i1; v1 = v0; i1 = i0; v0 = v; i0 = i; }
    else if (better(v, i, v1, i1)) { v2 = v1; i2 = i1; v1 = v; i1 = i; }
    else if (better(v, i, v2, i2)) { v2 = v; i2 = i; }
}

__global__ __launch_bounds__(64) void k_topk(const float* __restrict__ C,
                                             const float* __restrict__ Dh,
                                             float* __restrict__ topv,
                                             int* __restrict__ topi) {
    int r = blockIdx.x;
    int lane = threadIdx.x;
    float dr = Dh[r];
    const float* row = C + (size_t)r * U_N;
    float v0 = NEGV, v1 = NEGV, v2 = NEGV;
    int i0 = 0x7fffffff, i1 = 0x7fffffff, i2 = 0x7fffffff;
    for (int c = lane; c < U_N; c += 64) {
        float cv = row[c];
        float val = (cv > 0.f) ? cv * dr * Dh[c] : NEGV;
        if (better(val, c, v2, i2)) ins3(val, c, v0, i0, v1, i1, v2, i2);
    }
#pragma unroll
    for (int off = 1; off < 64; off <<= 1) {
        float ov0 = __shfl_xor(v0, off), ov1 = __shfl_xor(v1, off), ov2 = __shfl_xor(v2, off);
        int oi0 = __shfl_xor(i0, off), oi1 = __shfl_xor(i1, off), oi2 = __shfl_xor(i2, off);
        ins3(ov0, oi0, v0, i0, v1, i1, v2, i2);
        ins3(ov1, oi1, v0, i0, v1, i1, v2, i2);
        ins3(ov2, oi2, v0, i0, v1, i1, v2, i2);
    }
    if (lane == 0) {
        topv[r * 3 + 0] = v0; topi[r * 3 + 0] = i0;
        topv[r * 3 + 1] = v1; topi[r * 3 + 1] = i1;
        topv[r * 3 + 2] = v2; topi[r * 3 + 2] = i2;
    }
}

// ---------------- scatter S = T + T^T ----------------
__global__ __launch_bounds__(256) void k_scatter(const float* __restrict__ topv,
                                                 const int* __restrict__ topi,
                                                 float* __restrict__ out) {
    int r = blockIdx.x * 256 + threadIdx.x;
    if (r >= U_N) return;
#pragma unroll
    for (int k = 0; k < 3; ++k) {
        float v = topv[r * 3 + k];
        int c = topi[r * 3 + k];
        if (v > 0.f) {
            atomicAdd(&out[(size_t)r * U_N + c], 0.5f * v);
            atomicAdd(&out[(size_t)c * U_N + r], 0.5f * v);
        }
    }
}

extern "C" void kernel_launch(void* const* d_in, const int* in_sizes, int n_in,
                              void* d_out, int out_size, void* d_ws, size_t ws_size,
                              hipStream_t stream) {
    const float* x  = (const float*)d_in[0];
    const float* w1 = (const float*)d_in[1];
    const float* b1 = (const float*)d_in[2];
    const float* w2 = (const float*)d_in[3];
    const float* b2 = (const float*)d_in[4];
    const int* esrc = (const int*)d_in[5];
    const int* edst = (const int*)d_in[6];
    int E = in_sizes[5];
    float* out = (float*)d_out;

    // workspace layout (~83 MB)
    unsigned short* Abf = (unsigned short*)d_ws;      // U*I bf16 (64 MiB)
    float* C    = (float*)(Abf + (size_t)U_N * I_N);  // U*U
    float* Pu   = C + (size_t)U_N * U_N;              // U*H
    float* Pi   = Pu + (size_t)U_N * H_N;             // I*H
    int*   degu = (int*)(Pi + (size_t)I_N * H_N);     // U
    int*   degi = degu + U_N;                         // I
    float* du   = (float*)(degi + I_N);               // U
    float* di   = du + U_N;                           // I
    float* Dh   = di + I_N;                           // U
    float* topv = Dh + U_N;                           // U*3
    int*   topi = (int*)(topv + U_N * 3);             // U*3

    hipMemsetAsync(Abf, 0, (size_t)U_N * I_N * sizeof(unsigned short), stream);
    hipMemsetAsync(C, 0, (size_t)U_N * U_N * sizeof(float), stream);
    hipMemsetAsync(degu, 0, (size_t)(U_N + I_N) * sizeof(int), stream);
    hipMemsetAsync(out, 0, (size_t)out_size * sizeof(float), stream);

    k_deg<<<(E + 255) / 256, 256, 0, stream>>>(esrc, edst, E, degu, degi);
    k_node<<<(I_N + 255) / 256, 256, 0, stream>>>(degu, degi, du, di, Dh,
                                                  out + (size_t)U_N * U_N);
    k_proj_u<<<(U_N * H_N) / 256, 256, 0, stream>>>(x, w1, b1, du, Pu);
    k_proj_i<<<(I_N * H_N) / 256, 256, 0, stream>>>(x, w1, di, Pi);
    k_edge<<<(E + 255) / 256, 256, 0, stream>>>(esrc, edst, E, Pu, Pi, w2, b2, Abf);
    k_syrk<<<dim3(NPAIR, KSPLIT), 256, 0, stream>>>(Abf, C);
    k_topk<<<U_N, 64, 0, stream>>>(C, Dh, topv, topi);
    k_scatter<<<(U_N + 255) / 256, 256, 0, stream>>>(topv, topi, out);
}

// Round 4
// 533.721 us; speedup vs baseline: 2.7929x; 1.2249x over previous
//
#include <hip/hip_runtime.h>
#include <hip/hip_bf16.h>
#include <math.h>

// Problem constants (from reference)
#define U_N 2048
#define I_N 16384
#define F_N 64
#define H_N 32
#define KDIM 16384     // item dimension of A
#define NEGV (-1e30f)

typedef __attribute__((ext_vector_type(8))) short short8;   // 8 bf16 (4 VGPR)
typedef __attribute__((ext_vector_type(4))) float f32x4;    // MFMA accumulator

// f32 -> bf16 bits, round-to-nearest-even
__device__ __forceinline__ unsigned short f2bf(float f) {
    unsigned int u = __builtin_bit_cast(unsigned int, f);
    return (unsigned short)((u + 0x7fffu + ((u >> 16) & 1u)) >> 16);
}
__device__ __forceinline__ float bf2f(unsigned short h) {
    unsigned int u = ((unsigned int)h) << 16;
    return __builtin_bit_cast(float, u);
}

// async global -> LDS, 16B per lane (wave-uniform LDS base + lane*16)
__device__ __forceinline__ void gload16(const unsigned short* g, unsigned short* l) {
    __builtin_amdgcn_global_load_lds(
        (const __attribute__((address_space(1))) unsigned int*)g,
        (__attribute__((address_space(3))) unsigned int*)l, 16, 0, 0);
}

// ---------------- degrees ----------------
__global__ __launch_bounds__(256) void k_deg(const int* __restrict__ src,
                                             const int* __restrict__ dst, int E,
                                             int* __restrict__ deg_u,
                                             int* __restrict__ deg_i) {
    int e = blockIdx.x * 256 + threadIdx.x;
    if (e >= E) return;
    atomicAdd(&deg_u[src[e]], 1);
    atomicAdd(&deg_i[dst[e]], 1);
}

// ---------------- log1p degrees, Dh, d_u output ----------------
__global__ __launch_bounds__(256) void k_node(const int* __restrict__ deg_u,
                                              const int* __restrict__ deg_i,
                                              float* __restrict__ du,
                                              float* __restrict__ di,
                                              float* __restrict__ Dh,
                                              float* __restrict__ out_du) {
    int t = blockIdx.x * 256 + threadIdx.x;
    if (t < U_N) {
        float v = log1pf((float)deg_u[t]);
        du[t] = v;
        Dh[t] = sqrtf(v);
        out_du[t] = v;   // second output of the reference
    }
    if (t < I_N) di[t] = log1pf((float)deg_i[t]);
}

// ---------------- per-user projection P_u[u][j] ----------------
__global__ __launch_bounds__(256) void k_proj_u(const float* __restrict__ x,
                                                const float* __restrict__ w1,
                                                const float* __restrict__ b1,
                                                const float* __restrict__ du,
                                                float* __restrict__ Pu) {
    int t = blockIdx.x * 256 + threadIdx.x;
    if (t >= U_N * H_N) return;
    int u = t >> 5, j = t & 31;
    const float* xr = x + (size_t)u * F_N;
    const float* wr = w1 + (size_t)j * (2 * F_N + 2);
    float acc = b1[j] + du[u] * wr[64];
#pragma unroll
    for (int f = 0; f < F_N; ++f) acc = fmaf(xr[f], wr[f], acc);
    Pu[t] = acc;
}

// ---------------- per-item projection P_i[i][j] ----------------
__global__ __launch_bounds__(256) void k_proj_i(const float* __restrict__ x,
                                                const float* __restrict__ w1,
                                                const float* __restrict__ di,
                                                float* __restrict__ Pi) {
    int t = blockIdx.x * 256 + threadIdx.x;
    if (t >= I_N * H_N) return;
    int i = t >> 5, j = t & 31;
    const float* xr = x + (size_t)(U_N + i) * F_N;
    const float* wr = w1 + (size_t)j * (2 * F_N + 2) + 65;
    float acc = di[i] * wr[64];  // w1[j][129]
#pragma unroll
    for (int f = 0; f < F_N; ++f) acc = fmaf(xr[f], wr[f], acc);
    Pi[t] = acc;
}

// ---------------- per-edge weight + bf16 CAS-accumulate into A ----------------
__global__ __launch_bounds__(256) void k_edge(const int* __restrict__ src,
                                              const int* __restrict__ dst, int E,
                                              const float* __restrict__ Pu,
                                              const float* __restrict__ Pi,
                                              const float* __restrict__ w2,
                                              const float* __restrict__ b2,
                                              unsigned short* __restrict__ Abf) {
    int e = blockIdx.x * 256 + threadIdx.x;
    if (e >= E) return;
    int u = src[e], i = dst[e];
    const float4* pu = (const float4*)(Pu + (size_t)u * H_N);
    const float4* pi = (const float4*)(Pi + (size_t)i * H_N);
    const float4* wv = (const float4*)w2;
    float acc = b2[0];
#pragma unroll
    for (int q = 0; q < H_N / 4; ++q) {
        float4 a = pu[q], b = pi[q], w = wv[q];
        acc = fmaf(fmaxf(a.x + b.x, 0.f), w.x, acc);
        acc = fmaf(fmaxf(a.y + b.y, 0.f), w.y, acc);
        acc = fmaf(fmaxf(a.z + b.z, 0.f), w.z, acc);
        acc = fmaf(fmaxf(a.w + b.w, 0.f), w.w, acc);
    }
    float wgt = 1.0f / (1.0f + expf(-acc));

    // coalesce-sum duplicates in bf16 via 32-bit CAS (dups ~1.5% of edges)
    unsigned int idx = (unsigned int)u * (unsigned int)I_N + (unsigned int)i;
    unsigned int* word = (unsigned int*)Abf + (idx >> 1);
    unsigned int shift = (idx & 1u) * 16u;
    unsigned int cur = *word, assumed;
    do {
        assumed = cur;
        unsigned short h = (unsigned short)((assumed >> shift) & 0xffffu);
        unsigned short nh = f2bf(bf2f(h) + wgt);
        unsigned int nw = (assumed & ~(0xffffu << shift)) | ((unsigned int)nh << shift);
        cur = atomicCAS(word, assumed, nw);
    } while (cur != assumed);
}

// ---------------- C = A * A^T via bf16 MFMA, async LDS staging ----------------
// 128x128 tiles over symmetric block-pairs (bi<=bj), KSPLIT=8 partial-K
// (1088 blocks = 4.25/CU for latency hiding), BK=64 (32 barriers/block),
// global_load_lds (16B/lane) staging, 16x16x32 MFMA, upper-triangle-only
// fp32 atomicAdd epilogue (k_mirror fills the lower triangle afterwards).
#define BM 128
#define BK 64
#define NBLK (U_N / BM)                 // 16
#define NPAIR (NBLK * (NBLK + 1) / 2)   // 136
#define KSPLIT 8
#define KCH (KDIM / KSPLIT)             // 2048

__global__ __launch_bounds__(256) void k_syrk(const unsigned short* __restrict__ Abf,
                                              float* __restrict__ C) {
    __shared__ unsigned short As[BM * BK];   // 16 KB, 128B rows
    __shared__ unsigned short Bs[BM * BK];   // 16 KB

    // decode pair index -> (bi, bj), bi <= bj
    int p = blockIdx.x;
    int bi = 0, rem = p;
    while (rem >= NBLK - bi) { rem -= NBLK - bi; ++bi; }
    int bj = bi + rem;
    int k0 = blockIdx.y * KCH;
    int diag = (bi == bj);

    int tid = threadIdx.x;
    int wave = tid >> 6, lane = tid & 63;

    // staging: wave w fills rows [w*32, w*32+32) of each tile, 4 calls of
    // 8 rows each; lane l -> row (l>>3), 16B chunk (l&7) within the 8-row slab.
    int srow = wave * 32 + (lane >> 3);
    int scol = (lane & 7) * 8;
    const unsigned short* Ag = Abf + (size_t)(bi * BM + srow) * KDIM + k0 + scol;
    const unsigned short* Bg = Abf + (size_t)(bj * BM + srow) * KDIM + k0 + scol;
    unsigned short* lA = As + (wave * 32) * BK;   // wave-uniform bases
    unsigned short* lB = Bs + (wave * 32) * BK;

    // MFMA coords: 4 waves, each a 64x64 quadrant (4x4 of 16x16 tiles)
    int wm = wave >> 1, wn = wave & 1;
    int lm = lane & 15, lq = lane >> 4;
    const unsigned short* bTile = diag ? As : Bs;
    const unsigned short* aBase = As + (wm * 64 + lm) * BK + lq * 8;
    const unsigned short* bBase = bTile + (wn * 64 + lm) * BK + lq * 8;

    f32x4 acc[4][4];
#pragma unroll
    for (int m = 0; m < 4; ++m)
#pragma unroll
        for (int n = 0; n < 4; ++n) acc[m][n] = (f32x4){0.f, 0.f, 0.f, 0.f};

    for (int kt = 0; kt < KCH; kt += BK) {
        __syncthreads();              // previous tile fully consumed
#pragma unroll
        for (int j = 0; j < 4; ++j)
            gload16(Ag + kt + (size_t)(j * 8) * KDIM, lA + j * 8 * BK);
        if (!diag) {
#pragma unroll
            for (int j = 0; j < 4; ++j)
                gload16(Bg + kt + (size_t)(j * 8) * KDIM, lB + j * 8 * BK);
        }
        __syncthreads();              // vmcnt(0) drain -> tile ready

#pragma unroll
        for (int s = 0; s < 2; ++s) {
            short8 av[4], bv[4];
#pragma unroll
            for (int m = 0; m < 4; ++m)
                av[m] = *(const short8*)(aBase + m * 16 * BK + s * 32);
#pragma unroll
            for (int n = 0; n < 4; ++n)
                bv[n] = *(const short8*)(bBase + n * 16 * BK + s * 32);
#pragma unroll
            for (int m = 0; m < 4; ++m)
#pragma unroll
                for (int n = 0; n < 4; ++n)
                    acc[m][n] = __builtin_amdgcn_mfma_f32_16x16x32_bf16(
                        av[m], bv[n], acc[m][n], 0, 0, 0);
        }
    }

    // epilogue: C/D layout col=lane&15, row=lq*4+reg (m89-verified).
    // Upper-triangle tile only; k_mirror fills the lower triangle.
#pragma unroll
    for (int m = 0; m < 4; ++m) {
        int rb = bi * BM + wm * 64 + m * 16 + lq * 4;
#pragma unroll
        for (int n = 0; n < 4; ++n) {
            int c = bj * BM + wn * 64 + n * 16 + lm;
            f32x4 v = acc[m][n];
#pragma unroll
            for (int g = 0; g < 4; ++g)
                atomicAdd(&C[(size_t)(rb + g) * U_N + c], v[g]);
        }
    }
}

// ---------------- mirror lower triangle from upper ----------------
// 64x64 LDS-transpose tiles; only tiles strictly below the 128-block
// diagonal (diagonal 128-blocks are fully written by k_syrk).
__global__ __launch_bounds__(256) void k_mirror(float* __restrict__ C) {
    __shared__ float T[64][65];
    int tr = blockIdx.x, tc = blockIdx.y;   // dest 64-tile coords
    if ((tr >> 1) <= (tc >> 1)) return;     // keep only 128-block lower
    int lane = threadIdx.x & 63;
    int w = threadIdx.x >> 6;               // 0..3
#pragma unroll
    for (int s = 0; s < 16; ++s) {
        int r = s * 4 + w;
        T[r][lane] = C[(size_t)(tc * 64 + r) * U_N + tr * 64 + lane];
    }
    __syncthreads();
#pragma unroll
    for (int s = 0; s < 16; ++s) {
        int r = s * 4 + w;
        C[(size_t)(tr * 64 + r) * U_N + tc * 64 + lane] = T[lane][r];
    }
}

// ---------------- top-3 per row (scaled by Dh outer product) ----------------
__device__ __forceinline__ bool better(float va, int ia, float vb, int ib) {
    return (va > vb) || (va == vb && ia < ib);
}
__device__ __forceinline__ void ins3(float v, int i, float& v0, int& i0,
                                     float& v1, int& i1, float& v2, int& i2) {
    if (better(v, i, v0, i0)) { v2 = v1; i2 = i1; v1 = v0; i1 = i0; v0 = v; i0 = i; }
    else if (better(v, i, v1, i1)) { v2 = v1; i2 = i1; v1 = v; i1 = i; }
    else if (better(v, i, v2, i2)) { v2 = v; i2 = i; }
}

__global__ __launch_bounds__(64) void k_topk(const float* __restrict__ C,
                                             const float* __restrict__ Dh,
                                             float* __restrict__ topv,
                                             int* __restrict__ topi) {
    int r = blockIdx.x;
    int lane = threadIdx.x;
    float dr = Dh[r];
    const float* row = C + (size_t)r * U_N;
    float v0 = NEGV, v1 = NEGV, v2 = NEGV;
    int i0 = 0x7fffffff, i1 = 0x7fffffff, i2 = 0x7fffffff;
    for (int c = lane; c < U_N; c += 64) {
        float cv = row[c];
        float val = (cv > 0.f) ? cv * dr * Dh[c] : NEGV;
        if (better(val, c, v2, i2)) ins3(val, c, v0, i0, v1, i1, v2, i2);
    }
#pragma unroll
    for (int off = 1; off < 64; off <<= 1) {
        float ov0 = __shfl_xor(v0, off), ov1 = __shfl_xor(v1, off), ov2 = __shfl_xor(v2, off);
        int oi0 = __shfl_xor(i0, off), oi1 = __shfl_xor(i1, off), oi2 = __shfl_xor(i2, off);
        ins3(ov0, oi0, v0, i0, v1, i1, v2, i2);
        ins3(ov1, oi1, v0, i0, v1, i1, v2, i2);
        ins3(ov2, oi2, v0, i0, v1, i1, v2, i2);
    }
    if (lane == 0) {
        topv[r * 3 + 0] = v0; topi[r * 3 + 0] = i0;
        topv[r * 3 + 1] = v1; topi[r * 3 + 1] = i1;
        topv[r * 3 + 2] = v2; topi[r * 3 + 2] = i2;
    }
}

// ---------------- scatter S = T + T^T ----------------
__global__ __launch_bounds__(256) void k_scatter(const float* __restrict__ topv,
                                                 const int* __restrict__ topi,
                                                 float* __restrict__ out) {
    int r = blockIdx.x * 256 + threadIdx.x;
    if (r >= U_N) return;
#pragma unroll
    for (int k = 0; k < 3; ++k) {
        float v = topv[r * 3 + k];
        int c = topi[r * 3 + k];
        if (v > 0.f) {
            atomicAdd(&out[(size_t)r * U_N + c], 0.5f * v);
            atomicAdd(&out[(size_t)c * U_N + r], 0.5f * v);
        }
    }
}

extern "C" void kernel_launch(void* const* d_in, const int* in_sizes, int n_in,
                              void* d_out, int out_size, void* d_ws, size_t ws_size,
                              hipStream_t stream) {
    const float* x  = (const float*)d_in[0];
    const float* w1 = (const float*)d_in[1];
    const float* b1 = (const float*)d_in[2];
    const float* w2 = (const float*)d_in[3];
    const float* b2 = (const float*)d_in[4];
    const int* esrc = (const int*)d_in[5];
    const int* edst = (const int*)d_in[6];
    int E = in_sizes[5];
    float* out = (float*)d_out;

    // workspace layout (~83 MB)
    unsigned short* Abf = (unsigned short*)d_ws;      // U*I bf16 (64 MiB)
    float* C    = (float*)(Abf + (size_t)U_N * I_N);  // U*U
    float* Pu   = C + (size_t)U_N * U_N;              // U*H
    float* Pi   = Pu + (size_t)U_N * H_N;             // I*H
    int*   degu = (int*)(Pi + (size_t)I_N * H_N);     // U
    int*   degi = degu + U_N;                         // I
    float* du   = (float*)(degi + I_N);               // U
    float* di   = du + U_N;                           // I
    float* Dh   = di + I_N;                           // U
    float* topv = Dh + U_N;                           // U*3
    int*   topi = (int*)(topv + U_N * 3);             // U*3

    hipMemsetAsync(Abf, 0, (size_t)U_N * I_N * sizeof(unsigned short), stream);
    hipMemsetAsync(C, 0, (size_t)U_N * U_N * sizeof(float), stream);
    hipMemsetAsync(degu, 0, (size_t)(U_N + I_N) * sizeof(int), stream);
    hipMemsetAsync(out, 0, (size_t)out_size * sizeof(float), stream);

    k_deg<<<(E + 255) / 256, 256, 0, stream>>>(esrc, edst, E, degu, degi);
    k_node<<<(I_N + 255) / 256, 256, 0, stream>>>(degu, degi, du, di, Dh,
                                                  out + (size_t)U_N * U_N);
    k_proj_u<<<(U_N * H_N) / 256, 256, 0, stream>>>(x, w1, b1, du, Pu);
    k_proj_i<<<(I_N * H_N) / 256, 256, 0, stream>>>(x, w1, di, Pi);
    k_edge<<<(E + 255) / 256, 256, 0, stream>>>(esrc, edst, E, Pu, Pi, w2, b2, Abf);
    k_syrk<<<dim3(NPAIR, KSPLIT), 256, 0, stream>>>(Abf, C);
    k_mirror<<<dim3(U_N / 64, U_N / 64), 256, 0, stream>>>(C);
    k_topk<<<U_N, 64, 0, stream>>>(C, Dh, topv, topi);
    k_scatter<<<(U_N + 255) / 256, 256, 0, stream>>>(topv, topi, out);
}

// Round 5
// 376.269 us; speedup vs baseline: 3.9616x; 1.4185x over previous
//
#include <hip/hip_runtime.h>
#include <hip/hip_bf16.h>
#include <math.h>

// Problem constants (from reference)
#define U_N 2048
#define I_N 16384
#define F_N 64
#define H_N 32
#define KDIM 16384     // item dimension of A
#define NEGV (-1e30f)
#define NB_DEG 128     // partial-histogram blocks

typedef __attribute__((ext_vector_type(8))) short short8;   // 8 bf16 (4 VGPR)
typedef __attribute__((ext_vector_type(4))) float f32x4;    // MFMA accumulator

// f32 -> bf16 bits, round-to-nearest-even
__device__ __forceinline__ unsigned short f2bf(float f) {
    unsigned int u = __builtin_bit_cast(unsigned int, f);
    return (unsigned short)((u + 0x7fffu + ((u >> 16) & 1u)) >> 16);
}
__device__ __forceinline__ float bf2f(unsigned short h) {
    unsigned int u = ((unsigned int)h) << 16;
    return __builtin_bit_cast(float, u);
}

// async global -> LDS, 16B per lane (wave-uniform LDS base + lane*16)
__device__ __forceinline__ void gload16(const unsigned short* g, unsigned short* l) {
    __builtin_amdgcn_global_load_lds(
        (const __attribute__((address_space(1))) unsigned int*)g,
        (__attribute__((address_space(3))) unsigned int*)l, 16, 0, 0);
}

// ---------------- per-block LDS degree histograms ----------------
// users: u32[2048] (8 KB); items: packed 2 counters/word u32[8192] (32 KB).
// Flush is plain coalesced stores -> no cross-XCD atomic ping-pong.
__global__ __launch_bounds__(256) void k_deg_part(const int* __restrict__ src,
                                                  const int* __restrict__ dst, int E,
                                                  unsigned int* __restrict__ pu,
                                                  unsigned int* __restrict__ pi2) {
    __shared__ unsigned int hu[U_N];        // 8 KB
    __shared__ unsigned int hi2[I_N / 2];   // 32 KB
    int tid = threadIdx.x;
    for (int t = tid; t < U_N; t += 256) hu[t] = 0u;
    for (int t = tid; t < I_N / 2; t += 256) hi2[t] = 0u;
    __syncthreads();
    for (int e = blockIdx.x * 256 + tid; e < E; e += NB_DEG * 256) {
        int u = src[e], i = dst[e];
        atomicAdd(&hu[u], 1u);
        atomicAdd(&hi2[i >> 1], 1u << ((i & 1) * 16));
    }
    __syncthreads();
    unsigned int* pub = pu + (size_t)blockIdx.x * U_N;
    unsigned int* pib = pi2 + (size_t)blockIdx.x * (I_N / 2);
    for (int t = tid; t < U_N; t += 256) pub[t] = hu[t];
    for (int t = tid; t < I_N / 2; t += 256) pib[t] = hi2[t];
}

// ---------------- reduce partials, log1p, Dh, d_u output ----------------
__global__ __launch_bounds__(256) void k_node(const unsigned int* __restrict__ pu,
                                              const unsigned int* __restrict__ pi2,
                                              float* __restrict__ du,
                                              float* __restrict__ di,
                                              float* __restrict__ Dh,
                                              float* __restrict__ out_du) {
    int t = blockIdx.x * 256 + threadIdx.x;
    if (t < U_N) {
        unsigned int s = 0;
        for (int b = 0; b < NB_DEG; ++b) s += pu[(size_t)b * U_N + t];
        float v = log1pf((float)s);
        du[t] = v;
        Dh[t] = sqrtf(v);
        out_du[t] = v;   // second output of the reference
    }
    if (t < I_N / 2) {
        unsigned int s = 0;
        for (int b = 0; b < NB_DEG; ++b) s += pi2[(size_t)b * (I_N / 2) + t];
        di[2 * t]     = log1pf((float)(s & 0xffffu));
        di[2 * t + 1] = log1pf((float)(s >> 16));
    }
}

// ---------------- per-user projection P_u[u][j] ----------------
__global__ __launch_bounds__(256) void k_proj_u(const float* __restrict__ x,
                                                const float* __restrict__ w1,
                                                const float* __restrict__ b1,
                                                const float* __restrict__ du,
                                                float* __restrict__ Pu) {
    int t = blockIdx.x * 256 + threadIdx.x;
    if (t >= U_N * H_N) return;
    int u = t >> 5, j = t & 31;
    const float* xr = x + (size_t)u * F_N;
    const float* wr = w1 + (size_t)j * (2 * F_N + 2);
    float acc = b1[j] + du[u] * wr[64];
#pragma unroll
    for (int f = 0; f < F_N; ++f) acc = fmaf(xr[f], wr[f], acc);
    Pu[t] = acc;
}

// ---------------- per-item projection P_i[i][j] ----------------
__global__ __launch_bounds__(256) void k_proj_i(const float* __restrict__ x,
                                                const float* __restrict__ w1,
                                                const float* __restrict__ di,
                                                float* __restrict__ Pi) {
    int t = blockIdx.x * 256 + threadIdx.x;
    if (t >= I_N * H_N) return;
    int i = t >> 5, j = t & 31;
    const float* xr = x + (size_t)(U_N + i) * F_N;
    const float* wr = w1 + (size_t)j * (2 * F_N + 2) + 65;
    float acc = di[i] * wr[64];  // w1[j][129]
#pragma unroll
    for (int f = 0; f < F_N; ++f) acc = fmaf(xr[f], wr[f], acc);
    Pi[t] = acc;
}

// ---------------- per-edge weight + bf16 CAS-accumulate into A ----------------
__global__ __launch_bounds__(256) void k_edge(const int* __restrict__ src,
                                              const int* __restrict__ dst, int E,
                                              const float* __restrict__ Pu,
                                              const float* __restrict__ Pi,
                                              const float* __restrict__ w2,
                                              const float* __restrict__ b2,
                                              unsigned short* __restrict__ Abf) {
    int e = blockIdx.x * 256 + threadIdx.x;
    if (e >= E) return;
    int u = src[e], i = dst[e];
    const float4* pu = (const float4*)(Pu + (size_t)u * H_N);
    const float4* pi = (const float4*)(Pi + (size_t)i * H_N);
    const float4* wv = (const float4*)w2;
    float acc = b2[0];
#pragma unroll
    for (int q = 0; q < H_N / 4; ++q) {
        float4 a = pu[q], b = pi[q], w = wv[q];
        acc = fmaf(fmaxf(a.x + b.x, 0.f), w.x, acc);
        acc = fmaf(fmaxf(a.y + b.y, 0.f), w.y, acc);
        acc = fmaf(fmaxf(a.z + b.z, 0.f), w.z, acc);
        acc = fmaf(fmaxf(a.w + b.w, 0.f), w.w, acc);
    }
    float wgt = 1.0f / (1.0f + expf(-acc));

    // coalesce-sum duplicates in bf16 via 32-bit CAS (dups ~1.5% of edges)
    unsigned int idx = (unsigned int)u * (unsigned int)I_N + (unsigned int)i;
    unsigned int* word = (unsigned int*)Abf + (idx >> 1);
    unsigned int shift = (idx & 1u) * 16u;
    unsigned int cur = *word, assumed;
    do {
        assumed = cur;
        unsigned short h = (unsigned short)((assumed >> shift) & 0xffffu);
        unsigned short nh = f2bf(bf2f(h) + wgt);
        unsigned int nw = (assumed & ~(0xffffu << shift)) | ((unsigned int)nh << shift);
        cur = atomicCAS(word, assumed, nw);
    } while (cur != assumed);
}

// ---------------- C = A * A^T via bf16 MFMA, async LDS staging ----------------
#define BM 128
#define BK 64
#define NBLK (U_N / BM)                 // 16
#define NPAIR (NBLK * (NBLK + 1) / 2)   // 136
#define KSPLIT 8
#define KCH (KDIM / KSPLIT)             // 2048

__global__ __launch_bounds__(256) void k_syrk(const unsigned short* __restrict__ Abf,
                                              float* __restrict__ C) {
    __shared__ unsigned short As[BM * BK];   // 16 KB, 128B rows
    __shared__ unsigned short Bs[BM * BK];   // 16 KB

    // decode pair index -> (bi, bj), bi <= bj
    int p = blockIdx.x;
    int bi = 0, rem = p;
    while (rem >= NBLK - bi) { rem -= NBLK - bi; ++bi; }
    int bj = bi + rem;
    int k0 = blockIdx.y * KCH;
    int diag = (bi == bj);

    int tid = threadIdx.x;
    int wave = tid >> 6, lane = tid & 63;

    // staging: wave w fills rows [w*32, w*32+32) of each tile, 4 calls of
    // 8 rows each; lane l -> row (l>>3), 16B chunk (l&7) within the slab.
    int srow = wave * 32 + (lane >> 3);
    int scol = (lane & 7) * 8;
    const unsigned short* Ag = Abf + (size_t)(bi * BM + srow) * KDIM + k0 + scol;
    const unsigned short* Bg = Abf + (size_t)(bj * BM + srow) * KDIM + k0 + scol;
    unsigned short* lA = As + (wave * 32) * BK;   // wave-uniform bases
    unsigned short* lB = Bs + (wave * 32) * BK;

    // MFMA coords: 4 waves, each a 64x64 quadrant (4x4 of 16x16 tiles)
    int wm = wave >> 1, wn = wave & 1;
    int lm = lane & 15, lq = lane >> 4;
    const unsigned short* bTile = diag ? As : Bs;
    const unsigned short* aBase = As + (wm * 64 + lm) * BK + lq * 8;
    const unsigned short* bBase = bTile + (wn * 64 + lm) * BK + lq * 8;

    f32x4 acc[4][4];
#pragma unroll
    for (int m = 0; m < 4; ++m)
#pragma unroll
        for (int n = 0; n < 4; ++n) acc[m][n] = (f32x4){0.f, 0.f, 0.f, 0.f};

    for (int kt = 0; kt < KCH; kt += BK) {
        __syncthreads();              // previous tile fully consumed
#pragma unroll
        for (int j = 0; j < 4; ++j)
            gload16(Ag + kt + (size_t)(j * 8) * KDIM, lA + j * 8 * BK);
        if (!diag) {
#pragma unroll
            for (int j = 0; j < 4; ++j)
                gload16(Bg + kt + (size_t)(j * 8) * KDIM, lB + j * 8 * BK);
        }
        __syncthreads();              // vmcnt(0) drain -> tile ready

#pragma unroll
        for (int s = 0; s < 2; ++s) {
            short8 av[4], bv[4];
#pragma unroll
            for (int m = 0; m < 4; ++m)
                av[m] = *(const short8*)(aBase + m * 16 * BK + s * 32);
#pragma unroll
            for (int n = 0; n < 4; ++n)
                bv[n] = *(const short8*)(bBase + n * 16 * BK + s * 32);
#pragma unroll
            for (int m = 0; m < 4; ++m)
#pragma unroll
                for (int n = 0; n < 4; ++n)
                    acc[m][n] = __builtin_amdgcn_mfma_f32_16x16x32_bf16(
                        av[m], bv[n], acc[m][n], 0, 0, 0);
        }
    }

    // epilogue: C/D layout col=lane&15, row=lq*4+reg (m89-verified).
    // Upper-triangle tile only; k_mirror fills the lower triangle.
#pragma unroll
    for (int m = 0; m < 4; ++m) {
        int rb = bi * BM + wm * 64 + m * 16 + lq * 4;
#pragma unroll
        for (int n = 0; n < 4; ++n) {
            int c = bj * BM + wn * 64 + n * 16 + lm;
            f32x4 v = acc[m][n];
#pragma unroll
            for (int g = 0; g < 4; ++g)
                atomicAdd(&C[(size_t)(rb + g) * U_N + c], v[g]);
        }
    }
}

// ---------------- mirror lower triangle from upper ----------------
__global__ __launch_bounds__(256) void k_mirror(float* __restrict__ C) {
    __shared__ float T[64][65];
    int tr = blockIdx.x, tc = blockIdx.y;   // dest 64-tile coords
    if ((tr >> 1) <= (tc >> 1)) return;     // keep only 128-block lower
    int lane = threadIdx.x & 63;
    int w = threadIdx.x >> 6;               // 0..3
#pragma unroll
    for (int s = 0; s < 16; ++s) {
        int r = s * 4 + w;
        T[r][lane] = C[(size_t)(tc * 64 + r) * U_N + tr * 64 + lane];
    }
    __syncthreads();
#pragma unroll
    for (int s = 0; s < 16; ++s) {
        int r = s * 4 + w;
        C[(size_t)(tr * 64 + r) * U_N + tc * 64 + lane] = T[lane][r];
    }
}

// ---------------- top-3 per row (scaled by Dh outer product) ----------------
__device__ __forceinline__ bool better(float va, int ia, float vb, int ib) {
    return (va > vb) || (va == vb && ia < ib);
}
__device__ __forceinline__ void ins3(float v, int i, float& v0, int& i0,
                                     float& v1, int& i1, float& v2, int& i2) {
    if (better(v, i, v0, i0)) { v2 = v1; i2 = i1; v1 = v0; i1 = i0; v0 = v; i0 = i; }
    else if (better(v, i, v1, i1)) { v2 = v1; i2 = i1; v1 = v; i1 = i; }
    else if (better(v, i, v2, i2)) { v2 = v; i2 = i; }
}

__global__ __launch_bounds__(64) void k_topk(const float* __restrict__ C,
                                             const float* __restrict__ Dh,
                                             float* __restrict__ topv,
                                             int* __restrict__ topi) {
    int r = blockIdx.x;
    int lane = threadIdx.x;
    float dr = Dh[r];
    const float4* row = (const float4*)(C + (size_t)r * U_N);
    const float4* dh4 = (const float4*)Dh;
    float v0 = NEGV, v1 = NEGV, v2 = NEGV;
    int i0 = 0x7fffffff, i1 = 0x7fffffff, i2 = 0x7fffffff;
    for (int q = lane; q < U_N / 4; q += 64) {
        float4 cv = row[q];
        float4 dv = dh4[q];
        int c = q * 4;
        float x0 = (cv.x > 0.f) ? cv.x * dr * dv.x : NEGV;
        float x1 = (cv.y > 0.f) ? cv.y * dr * dv.y : NEGV;
        float x2 = (cv.z > 0.f) ? cv.z * dr * dv.z : NEGV;
        float x3 = (cv.w > 0.f) ? cv.w * dr * dv.w : NEGV;
        if (better(x0, c + 0, v2, i2)) ins3(x0, c + 0, v0, i0, v1, i1, v2, i2);
        if (better(x1, c + 1, v2, i2)) ins3(x1, c + 1, v0, i0, v1, i1, v2, i2);
        if (better(x2, c + 2, v2, i2)) ins3(x2, c + 2, v0, i0, v1, i1, v2, i2);
        if (better(x3, c + 3, v2, i2)) ins3(x3, c + 3, v0, i0, v1, i1, v2, i2);
    }
#pragma unroll
    for (int off = 1; off < 64; off <<= 1) {
        float ov0 = __shfl_xor(v0, off), ov1 = __shfl_xor(v1, off), ov2 = __shfl_xor(v2, off);
        int oi0 = __shfl_xor(i0, off), oi1 = __shfl_xor(i1, off), oi2 = __shfl_xor(i2, off);
        ins3(ov0, oi0, v0, i0, v1, i1, v2, i2);
        ins3(ov1, oi1, v0, i0, v1, i1, v2, i2);
        ins3(ov2, oi2, v0, i0, v1, i1, v2, i2);
    }
    if (lane == 0) {
        topv[r * 3 + 0] = v0; topi[r * 3 + 0] = i0;
        topv[r * 3 + 1] = v1; topi[r * 3 + 1] = i1;
        topv[r * 3 + 2] = v2; topi[r * 3 + 2] = i2;
    }
}

// ---------------- scatter S = T + T^T ----------------
__global__ __launch_bounds__(256) void k_scatter(const float* __restrict__ topv,
                                                 const int* __restrict__ topi,
                                                 float* __restrict__ out) {
    int r = blockIdx.x * 256 + threadIdx.x;
    if (r >= U_N) return;
#pragma unroll
    for (int k = 0; k < 3; ++k) {
        float v = topv[r * 3 + k];
        int c = topi[r * 3 + k];
        if (v > 0.f) {
            atomicAdd(&out[(size_t)r * U_N + c], 0.5f * v);
            atomicAdd(&out[(size_t)c * U_N + r], 0.5f * v);
        }
    }
}

extern "C" void kernel_launch(void* const* d_in, const int* in_sizes, int n_in,
                              void* d_out, int out_size, void* d_ws, size_t ws_size,
                              hipStream_t stream) {
    const float* x  = (const float*)d_in[0];
    const float* w1 = (const float*)d_in[1];
    const float* b1 = (const float*)d_in[2];
    const float* w2 = (const float*)d_in[3];
    const float* b2 = (const float*)d_in[4];
    const int* esrc = (const int*)d_in[5];
    const int* edst = (const int*)d_in[6];
    int E = in_sizes[5];
    float* out = (float*)d_out;

    // workspace layout (~88 MB)
    unsigned short* Abf = (unsigned short*)d_ws;          // U*I bf16 (64 MiB)
    float* C    = (float*)(Abf + (size_t)U_N * I_N);      // U*U (16 MiB), contiguous after Abf
    float* Pu   = C + (size_t)U_N * U_N;                  // U*H
    float* Pi   = Pu + (size_t)U_N * H_N;                 // I*H
    unsigned int* pu  = (unsigned int*)(Pi + (size_t)I_N * H_N);  // NB_DEG*U
    unsigned int* pi2 = pu + (size_t)NB_DEG * U_N;        // NB_DEG*I/2
    float* du   = (float*)(pi2 + (size_t)NB_DEG * (I_N / 2));     // U
    float* di   = du + U_N;                               // I
    float* Dh   = di + I_N;                               // U
    float* topv = Dh + U_N;                               // U*3
    int*   topi = (int*)(topv + U_N * 3);                 // U*3

    // one memset covers Abf (bf16) + C (fp32) contiguously; out separately.
    hipMemsetAsync(Abf, 0,
                   (size_t)U_N * I_N * sizeof(unsigned short) +
                   (size_t)U_N * U_N * sizeof(float), stream);
    hipMemsetAsync(out, 0, (size_t)out_size * sizeof(float), stream);

    k_deg_part<<<NB_DEG, 256, 0, stream>>>(esrc, edst, E, pu, pi2);
    k_node<<<(I_N / 2 + 255) / 256, 256, 0, stream>>>(pu, pi2, du, di, Dh,
                                                      out + (size_t)U_N * U_N);
    k_proj_u<<<(U_N * H_N) / 256, 256, 0, stream>>>(x, w1, b1, du, Pu);
    k_proj_i<<<(I_N * H_N) / 256, 256, 0, stream>>>(x, w1, di, Pi);
    k_edge<<<(E + 255) / 256, 256, 0, stream>>>(esrc, edst, E, Pu, Pi, w2, b2, Abf);
    k_syrk<<<dim3(NPAIR, KSPLIT), 256, 0, stream>>>(Abf, C);
    k_mirror<<<dim3(U_N / 64, U_N / 64), 256, 0, stream>>>(C);
    k_topk<<<U_N, 64, 0, stream>>>(C, Dh, topv, topi);
    k_scatter<<<(U_N + 255) / 256, 256, 0, stream>>>(topv, topi, out);
}